// Round 3
// baseline (350.882 us; speedup 1.0000x reference)
//
#include <hip/hip_runtime.h>
#include <math.h>

#define B_ROWS 65536
#define N_COLS 512
#define EPS 1e-8f
#define NREP 8
#define GRID1 2048   // 8192 waves x 4 rows/iter x 2 iters = 65536 rows
#define GRID2 2048

// ws layout (floats):
//   [0, B_ROWS)                  sim
//   [B_ROWS, +NREP*512)          colsum replicas
//   [B_ROWS+NREP*512, +4)        acc[0]=sum max(log sim,-100)
//                                acc[1]=sum max(sim,e)*max(log sim,e)
//                                acc[2]=sum max(toe,e)*max(log toe,e)

__global__ __launch_bounds__(256) void scan_pass1(
        const float* __restrict__ A, const float* __restrict__ Bn,
        float* __restrict__ sim, float* __restrict__ colsum,
        float* __restrict__ acc) {
    __shared__ float cs[512];
    __shared__ float sred[8];

    const int t    = threadIdx.x;
    const int lane = t & 63;
    const int sub  = lane & 15;     // position within quarter-wave (16 lanes/row)
    const int g    = lane >> 4;     // which of the 4 rows this lane serves
    const int wave = (blockIdx.x * 256 + t) >> 6;   // 0..8191

    float cacc[32];
#pragma unroll
    for (int k = 0; k < 32; ++k) cacc[k] = 0.f;
    float accLog = 0.f, accSec = 0.f;

#pragma unroll
    for (int iter = 0; iter < 2; ++iter) {
        const int row = wave * 4 + g + iter * 32768;
        const float* a = A  + (size_t)row * N_COLS;
        const float* b = Bn + (size_t)row * N_COLS;

        // lane's float4 chunks: index k*16+sub -> cols 64k+4*sub+c
        float4 av4[8], bv4[8];
#pragma unroll
        for (int k = 0; k < 8; ++k) {
            av4[k] = *(const float4*)(a + (k * 16 + sub) * 4);
            bv4[k] = *(const float4*)(b + (k * 16 + sub) * 4);
        }

        // inputs ~N(0,1): fp32 exp cannot overflow — skip max-subtraction
        float ea[32];
        float sa = 0.f, sb = 0.f, dp = 0.f;
#pragma unroll
        for (int k = 0; k < 8; ++k) {
            float avv[4] = {av4[k].x, av4[k].y, av4[k].z, av4[k].w};
            float bvv[4] = {bv4[k].x, bv4[k].y, bv4[k].z, bv4[k].w};
#pragma unroll
            for (int c = 0; c < 4; ++c) {
                float e = __expf(avv[c]);
                float f = __expf(bvv[c]);
                ea[k * 4 + c] = e;
                sa += e; sb += f; dp += e * f;
            }
        }

        // reduce across the 16 lanes of this row (masks stay within group)
#pragma unroll
        for (int m = 8; m >= 1; m >>= 1) {
            sa += __shfl_xor(sa, m, 64);
            sb += __shfl_xor(sb, m, 64);
            dp += __shfl_xor(dp, m, 64);
        }

        float inv_sa = 1.f / sa;
#pragma unroll
        for (int k = 0; k < 32; ++k) cacc[k] += ea[k] * inv_sa;

        if (sub == 0) {
            float s = dp * inv_sa * (1.f / sb);
            sim[row] = s;
            float lg = __logf(s);
            accLog += fmaxf(lg, -100.f);
            accSec += fmaxf(s, EPS) * fmaxf(lg, EPS);
        }
    }

    // ---- epilogue: block-level reductions ----
    // scalar accumulators: only sub==0 lanes hold nonzero; fold groups
    accLog += __shfl_xor(accLog, 16, 64); accLog += __shfl_xor(accLog, 32, 64);
    accSec += __shfl_xor(accSec, 16, 64); accSec += __shfl_xor(accSec, 32, 64);

    cs[t] = 0.f; cs[t + 256] = 0.f;
    __syncthreads();
#pragma unroll
    for (int k = 0; k < 8; ++k)
#pragma unroll
        for (int c = 0; c < 4; ++c)
            atomicAdd(&cs[64 * k + 4 * sub + c], cacc[k * 4 + c]);
    if (lane == 0) { sred[(t >> 6)] = accLog; sred[4 + (t >> 6)] = accSec; }
    __syncthreads();

    float* crep = colsum + (blockIdx.x & (NREP - 1)) * 512;
    atomicAdd(&crep[t], cs[t]);
    atomicAdd(&crep[t + 256], cs[t + 256]);
    if (t == 0)
        atomicAdd(&acc[0], sred[0] + sred[1] + sred[2] + sred[3]);
    if (t == 1)
        atomicAdd(&acc[1], sred[4] + sred[5] + sred[6] + sred[7]);
}

__global__ __launch_bounds__(256) void scan_pass2(
        const float* __restrict__ A, const float* __restrict__ sim,
        float* __restrict__ acc) {
    __shared__ float sred[4];
    const int t    = threadIdx.x;
    const int lane = t & 63;
    const int sub  = lane & 15;
    const int g    = lane >> 4;
    const int wave = (blockIdx.x * 256 + t) >> 6;

    // slab index (row & 127) is invariant across both iterations
    const int slab = (wave * 4 + g) & 127;
    const float* sp = sim + (size_t)slab * N_COLS;
    float4 sv4[8];
#pragma unroll
    for (int k = 0; k < 8; ++k)
        sv4[k] = *(const float4*)(sp + (k * 16 + sub) * 4);

    float accThird = 0.f;
#pragma unroll
    for (int iter = 0; iter < 2; ++iter) {
        const int row = wave * 4 + g + iter * 32768;
        const float* a = A + (size_t)row * N_COLS;
        float4 av4[8];
#pragma unroll
        for (int k = 0; k < 8; ++k)
            av4[k] = *(const float4*)(a + (k * 16 + sub) * 4);

        float sa = 0.f, dp = 0.f;
#pragma unroll
        for (int k = 0; k < 8; ++k) {
            float avv[4] = {av4[k].x, av4[k].y, av4[k].z, av4[k].w};
            float svv[4] = {sv4[k].x, sv4[k].y, sv4[k].z, sv4[k].w};
#pragma unroll
            for (int c = 0; c < 4; ++c) {
                float e = __expf(avv[c]);
                sa += e;
                dp += e * svv[c];
            }
        }
#pragma unroll
        for (int m = 8; m >= 1; m >>= 1) {
            sa += __shfl_xor(sa, m, 64);
            dp += __shfl_xor(dp, m, 64);
        }
        if (sub == 0) {
            float toe = dp / sa;
            float lg  = __logf(toe);
            accThird += fmaxf(toe, EPS) * fmaxf(lg, EPS);
        }
    }

    accThird += __shfl_xor(accThird, 16, 64);
    accThird += __shfl_xor(accThird, 32, 64);
    if (lane == 0) sred[t >> 6] = accThird;
    __syncthreads();
    if (t == 0)
        atomicAdd(&acc[2], sred[0] + sred[1] + sred[2] + sred[3]);
}

__global__ __launch_bounds__(64) void scan_finalize(
        const float* __restrict__ colsum, const float* __restrict__ acc,
        float* __restrict__ out) {
    const int lane = threadIdx.x;
    float e = 0.f;
#pragma unroll
    for (int k = 0; k < 8; ++k) {
        const int col = lane * 8 + k;
        float c = 0.f;
#pragma unroll
        for (int r = 0; r < NREP; ++r) c += colsum[r * 512 + col];
        float p = c * (1.f / B_ROWS);
        p = fmaxf(p, EPS);
        e -= p * __logf(p);
    }
#pragma unroll
    for (int m = 32; m >= 1; m >>= 1) e += __shfl_xor(e, m, 64);
    if (lane == 0) {
        float consistency = -acc[0] * (1.f / B_ROWS);
        float second      = acc[1];
        float third       = acc[2] * (1.f / N_COLS);
        float entropy     = e;
        float third_weight = 0.5f / sqrtf((float)N_COLS);
        float diff_weight  = 0.25f / (float)N_COLS;
        float total = consistency - 2.0f * entropy + diff_weight * second
                      - third_weight * third;
        out[0] = total;
        out[1] = consistency;
        out[2] = entropy;
        out[3] = second;
        out[4] = third;
    }
}

extern "C" void kernel_launch(void* const* d_in, const int* in_sizes, int n_in,
                              void* d_out, int out_size, void* d_ws, size_t ws_size,
                              hipStream_t stream) {
    const float* anchors   = (const float*)d_in[0];
    const float* neighbors = (const float*)d_in[1];
    float* out = (float*)d_out;

    float* sim    = (float*)d_ws;
    float* colsum = sim + B_ROWS;
    float* acc    = colsum + NREP * 512;

    hipMemsetAsync(colsum, 0, (NREP * 512 + 4) * sizeof(float), stream);

    scan_pass1<<<dim3(GRID1), dim3(256), 0, stream>>>(anchors, neighbors, sim, colsum, acc);
    scan_pass2<<<dim3(GRID2), dim3(256), 0, stream>>>(anchors, sim, acc);
    scan_finalize<<<1, 64, 0, stream>>>(colsum, acc, out);
}

// Round 4
// 333.844 us; speedup vs baseline: 1.0510x; 1.0510x over previous
//
#include <hip/hip_runtime.h>
#include <math.h>

#define B_ROWS 65536
#define N_COLS 512
#define EPS 1e-8f
#define NREP 8
#define GRID1 2048   // 8192 waves, 8 rows each
#define GRID2 2048

// ws layout (floats):
//   [0, 65536)            sim
//   [65536, +NREP*512)    colsum replicas
//   [.., +16)             acc[0..2] (+pad to 64B)
//   then P: 65536x512 bf16 (64 MiB), if ws_size permits

__device__ __forceinline__ unsigned int pack_bf16_2(float lo, float hi) {
    unsigned int ulo = __float_as_uint(lo);
    unsigned int uhi = __float_as_uint(hi);
    ulo = (ulo + 0x7FFFu + ((ulo >> 16) & 1u)) >> 16;
    uhi = (uhi + 0x7FFFu + ((uhi >> 16) & 1u)) & 0xFFFF0000u;
    return ulo | uhi;
}

__global__ __launch_bounds__(256) void k1_sims(
        const float* __restrict__ A, const float* __restrict__ Bn,
        float* __restrict__ sim, unsigned int* __restrict__ Pb,
        float* __restrict__ acc, int storeP) {
    __shared__ float sred[8];
    const int t    = threadIdx.x;
    const int lane = t & 63;
    const int wave = (blockIdx.x * 256 + t) >> 6;   // 0..8191

    float accLog = 0.f, accSec = 0.f;

#pragma unroll
    for (int batch = 0; batch < 2; ++batch) {
        // ---- issue all 16 loads for 4 rows up front (max MLP) ----
        float4 a0[4], a1[4], b0[4], b1[4];
#pragma unroll
        for (int q = 0; q < 4; ++q) {
            const int row = wave + (q + batch * 4) * 8192;
            const float* a = A  + (size_t)row * N_COLS;
            const float* b = Bn + (size_t)row * N_COLS;
            a0[q] = *(const float4*)(a + lane * 4);
            a1[q] = *(const float4*)(a + 256 + lane * 4);
            b0[q] = *(const float4*)(b + lane * 4);
            b1[q] = *(const float4*)(b + 256 + lane * 4);
        }
        // ---- exp + per-lane partials (inputs ~N(0,1): no overflow) ----
        float ea[4][8], sa[4], sb[4], dp[4];
#pragma unroll
        for (int q = 0; q < 4; ++q) {
            float av[8] = {a0[q].x, a0[q].y, a0[q].z, a0[q].w,
                           a1[q].x, a1[q].y, a1[q].z, a1[q].w};
            float bv[8] = {b0[q].x, b0[q].y, b0[q].z, b0[q].w,
                           b1[q].x, b1[q].y, b1[q].z, b1[q].w};
            float s = 0.f, sB = 0.f, d = 0.f;
#pragma unroll
            for (int k = 0; k < 8; ++k) {
                float e = __expf(av[k]);
                float f = __expf(bv[k]);
                ea[q][k] = e;
                s += e; sB += f; d += e * f;
            }
            sa[q] = s; sb[q] = sB; dp[q] = d;
        }
        // ---- 12 independent shuffle chains, pipelined ----
#pragma unroll
        for (int m = 32; m >= 1; m >>= 1) {
#pragma unroll
            for (int q = 0; q < 4; ++q) {
                sa[q] += __shfl_xor(sa[q], m, 64);
                sb[q] += __shfl_xor(sb[q], m, 64);
                dp[q] += __shfl_xor(dp[q], m, 64);
            }
        }
        // ---- emit sim, scalars, bf16 P ----
#pragma unroll
        for (int q = 0; q < 4; ++q) {
            const int row = wave + (q + batch * 4) * 8192;
            float inv_sa = 1.f / sa[q];
            float s = dp[q] * inv_sa * (1.f / sb[q]);
            if (lane == 0) {
                sim[row] = s;
                float lg = __logf(s);
                accLog += fmaxf(lg, -100.f);
                accSec += fmaxf(s, EPS) * fmaxf(lg, EPS);
            }
            if (storeP) {
                float p[8];
#pragma unroll
                for (int k = 0; k < 8; ++k) p[k] = ea[q][k] * inv_sa;
                uint2 wlo, whi;
                wlo.x = pack_bf16_2(p[0], p[1]);
                wlo.y = pack_bf16_2(p[2], p[3]);
                whi.x = pack_bf16_2(p[4], p[5]);
                whi.y = pack_bf16_2(p[6], p[7]);
                unsigned int* pr = Pb + (size_t)row * 256;
                *(uint2*)(pr + lane * 2)       = wlo;   // cols lane*4+0..3
                *(uint2*)(pr + 128 + lane * 2) = whi;   // cols 256+lane*4+0..3
            }
        }
    }

    if (lane == 0) { sred[t >> 6] = accLog; sred[4 + (t >> 6)] = accSec; }
    __syncthreads();
    if (t == 0) atomicAdd(&acc[0], sred[0] + sred[1] + sred[2] + sred[3]);
    if (t == 1) atomicAdd(&acc[1], sred[4] + sred[5] + sred[6] + sred[7]);
}

// pass2 from bf16 P: colsum accumulation + third-order dot. No exp needed:
// toe_i = sum_j P_ij * sim[(i&127)*512 + j]   (P rows sum to 1)
__global__ __launch_bounds__(256) void k2_fromP(
        const unsigned int* __restrict__ Pb, const float* __restrict__ sim,
        float* __restrict__ colsum, float* __restrict__ acc) {
    __shared__ float cs[512];
    __shared__ float sred[4];
    const int t    = threadIdx.x;
    const int lane = t & 63;
    const int wave = (blockIdx.x * 256 + t) >> 6;

    // slab index (row & 127) is wave-invariant (row strides are %128==0)
    const float* sp = sim + (size_t)(wave & 127) * N_COLS;
    float4 sv0 = *(const float4*)(sp + lane * 4);
    float4 sv1 = *(const float4*)(sp + 256 + lane * 4);
    const float sv[8] = {sv0.x, sv0.y, sv0.z, sv0.w, sv1.x, sv1.y, sv1.z, sv1.w};

    float cacc[8];
#pragma unroll
    for (int k = 0; k < 8; ++k) cacc[k] = 0.f;
    float accThird = 0.f;

#pragma unroll
    for (int batch = 0; batch < 2; ++batch) {
        uint2 wlo[4], whi[4];
#pragma unroll
        for (int q = 0; q < 4; ++q) {
            const int row = wave + (q + batch * 4) * 8192;
            const unsigned int* pr = Pb + (size_t)row * 256;
            wlo[q] = *(const uint2*)(pr + lane * 2);
            whi[q] = *(const uint2*)(pr + 128 + lane * 2);
        }
        float dp[4];
#pragma unroll
        for (int q = 0; q < 4; ++q) {
            float p[8];
            p[0] = __uint_as_float(wlo[q].x << 16);
            p[1] = __uint_as_float(wlo[q].x & 0xFFFF0000u);
            p[2] = __uint_as_float(wlo[q].y << 16);
            p[3] = __uint_as_float(wlo[q].y & 0xFFFF0000u);
            p[4] = __uint_as_float(whi[q].x << 16);
            p[5] = __uint_as_float(whi[q].x & 0xFFFF0000u);
            p[6] = __uint_as_float(whi[q].y << 16);
            p[7] = __uint_as_float(whi[q].y & 0xFFFF0000u);
            float d = 0.f;
#pragma unroll
            for (int k = 0; k < 8; ++k) {
                cacc[k] += p[k];
                d += p[k] * sv[k];
            }
            dp[q] = d;
        }
#pragma unroll
        for (int m = 32; m >= 1; m >>= 1)
#pragma unroll
            for (int q = 0; q < 4; ++q) dp[q] += __shfl_xor(dp[q], m, 64);
        if (lane == 0) {
#pragma unroll
            for (int q = 0; q < 4; ++q) {
                float toe = dp[q];
                float lg  = __logf(toe);
                accThird += fmaxf(toe, EPS) * fmaxf(lg, EPS);
            }
        }
    }

    cs[t] = 0.f; cs[t + 256] = 0.f;
    __syncthreads();
#pragma unroll
    for (int k = 0; k < 4; ++k) atomicAdd(&cs[lane * 4 + k], cacc[k]);
#pragma unroll
    for (int k = 0; k < 4; ++k) atomicAdd(&cs[256 + lane * 4 + k], cacc[4 + k]);
    if (lane == 0) sred[t >> 6] = accThird;
    __syncthreads();
    float* crep = colsum + (blockIdx.x & (NREP - 1)) * 512;
    atomicAdd(&crep[t], cs[t]);
    atomicAdd(&crep[t + 256], cs[t + 256]);
    if (t == 0) atomicAdd(&acc[2], sred[0] + sred[1] + sred[2] + sred[3]);
}

// fallback pass2 when ws has no room for P: re-read A, recompute softmax,
// and also accumulate colsum here (since k1 no longer does).
__global__ __launch_bounds__(256) void k2_direct(
        const float* __restrict__ A, const float* __restrict__ sim,
        float* __restrict__ colsum, float* __restrict__ acc) {
    __shared__ float cs[512];
    __shared__ float sred[4];
    const int t    = threadIdx.x;
    const int lane = t & 63;
    const int wave = (blockIdx.x * 256 + t) >> 6;

    const float* sp = sim + (size_t)(wave & 127) * N_COLS;
    float4 sv0 = *(const float4*)(sp + lane * 4);
    float4 sv1 = *(const float4*)(sp + 256 + lane * 4);
    const float sv[8] = {sv0.x, sv0.y, sv0.z, sv0.w, sv1.x, sv1.y, sv1.z, sv1.w};

    float cacc[8];
#pragma unroll
    for (int k = 0; k < 8; ++k) cacc[k] = 0.f;
    float accThird = 0.f;

#pragma unroll
    for (int batch = 0; batch < 2; ++batch) {
        float4 a0[4], a1[4];
#pragma unroll
        for (int q = 0; q < 4; ++q) {
            const int row = wave + (q + batch * 4) * 8192;
            const float* a = A + (size_t)row * N_COLS;
            a0[q] = *(const float4*)(a + lane * 4);
            a1[q] = *(const float4*)(a + 256 + lane * 4);
        }
        float ea[4][8], sa[4], dp[4];
#pragma unroll
        for (int q = 0; q < 4; ++q) {
            float av[8] = {a0[q].x, a0[q].y, a0[q].z, a0[q].w,
                           a1[q].x, a1[q].y, a1[q].z, a1[q].w};
            float s = 0.f, d = 0.f;
#pragma unroll
            for (int k = 0; k < 8; ++k) {
                float e = __expf(av[k]);
                ea[q][k] = e;
                s += e;
                d += e * sv[k];
            }
            sa[q] = s; dp[q] = d;
        }
#pragma unroll
        for (int m = 32; m >= 1; m >>= 1)
#pragma unroll
            for (int q = 0; q < 4; ++q) {
                sa[q] += __shfl_xor(sa[q], m, 64);
                dp[q] += __shfl_xor(dp[q], m, 64);
            }
#pragma unroll
        for (int q = 0; q < 4; ++q) {
            float inv_sa = 1.f / sa[q];
#pragma unroll
            for (int k = 0; k < 8; ++k) cacc[k] += ea[q][k] * inv_sa;
            if (lane == 0) {
                float toe = dp[q] * inv_sa;
                float lg  = __logf(toe);
                accThird += fmaxf(toe, EPS) * fmaxf(lg, EPS);
            }
        }
    }

    cs[t] = 0.f; cs[t + 256] = 0.f;
    __syncthreads();
#pragma unroll
    for (int k = 0; k < 4; ++k) atomicAdd(&cs[lane * 4 + k], cacc[k]);
#pragma unroll
    for (int k = 0; k < 4; ++k) atomicAdd(&cs[256 + lane * 4 + k], cacc[4 + k]);
    if (lane == 0) sred[t >> 6] = accThird;
    __syncthreads();
    float* crep = colsum + (blockIdx.x & (NREP - 1)) * 512;
    atomicAdd(&crep[t], cs[t]);
    atomicAdd(&crep[t + 256], cs[t + 256]);
    if (t == 0) atomicAdd(&acc[2], sred[0] + sred[1] + sred[2] + sred[3]);
}

__global__ __launch_bounds__(64) void scan_finalize(
        const float* __restrict__ colsum, const float* __restrict__ acc,
        float* __restrict__ out) {
    const int lane = threadIdx.x;
    float e = 0.f;
#pragma unroll
    for (int k = 0; k < 8; ++k) {
        const int col = lane * 8 + k;
        float c = 0.f;
#pragma unroll
        for (int r = 0; r < NREP; ++r) c += colsum[r * 512 + col];
        float p = c * (1.f / B_ROWS);
        p = fmaxf(p, EPS);
        e -= p * __logf(p);
    }
#pragma unroll
    for (int m = 32; m >= 1; m >>= 1) e += __shfl_xor(e, m, 64);
    if (lane == 0) {
        float consistency = -acc[0] * (1.f / B_ROWS);
        float second      = acc[1];
        float third       = acc[2] * (1.f / N_COLS);
        float entropy     = e;
        float third_weight = 0.5f / sqrtf((float)N_COLS);
        float diff_weight  = 0.25f / (float)N_COLS;
        float total = consistency - 2.0f * entropy + diff_weight * second
                      - third_weight * third;
        out[0] = total;
        out[1] = consistency;
        out[2] = entropy;
        out[3] = second;
        out[4] = third;
    }
}

extern "C" void kernel_launch(void* const* d_in, const int* in_sizes, int n_in,
                              void* d_out, int out_size, void* d_ws, size_t ws_size,
                              hipStream_t stream) {
    const float* anchors   = (const float*)d_in[0];
    const float* neighbors = (const float*)d_in[1];
    float* out = (float*)d_out;

    float* sim    = (float*)d_ws;                     // 65536 f32
    float* colsum = sim + B_ROWS;                     // NREP*512 f32
    float* acc    = colsum + NREP * 512;              // 16 f32 (3 used + pad)
    unsigned int* Pb = (unsigned int*)(acc + 16);     // 64 MiB bf16 P
    const size_t need = (size_t)(B_ROWS + NREP * 512 + 16) * 4
                      + (size_t)B_ROWS * N_COLS * 2;
    const int haveP = (ws_size >= need) ? 1 : 0;

    hipMemsetAsync(colsum, 0, (NREP * 512 + 16) * sizeof(float), stream);

    k1_sims<<<dim3(GRID1), dim3(256), 0, stream>>>(
        anchors, neighbors, sim, Pb, acc, haveP);
    if (haveP)
        k2_fromP<<<dim3(GRID2), dim3(256), 0, stream>>>(Pb, sim, colsum, acc);
    else
        k2_direct<<<dim3(GRID2), dim3(256), 0, stream>>>(anchors, sim, colsum, acc);
    scan_finalize<<<1, 64, 0, stream>>>(colsum, acc, out);
}

// Round 5
// 297.588 us; speedup vs baseline: 1.1791x; 1.1218x over previous
//
#include <hip/hip_runtime.h>
#include <math.h>

#define B_ROWS 65536
#define N_COLS 512
#define EPS 1e-8f
#define GRID1 2048   // 2048 blocks x 4 waves x 8 rows = 65536 rows

// ws layout (floats):
//   [0, 65536)        sim
//   [65536, +128*512) colsum per residue s=row&127 (colsum_s[j] = sum of P_ij
//                     over rows i with i&127==s) -- 256 KB
//   [.., +16)         acc[0]=sum max(log sim,-100), acc[1]=sum max(sim,eps)
//
// Algebraic eliminations (valid because sim<1 and toe<1 strictly, so
// max(log(.),EPS) == EPS exactly, matching the reference bit-for-bit in
// effect): second = EPS * sum(sim); sum(toe) = sum_s <colsum_s, simslab_s>.
// This removes the entire second pass over A/P (128/64 MB of traffic).

__global__ __launch_bounds__(256) void k_main(
        const float* __restrict__ A, const float* __restrict__ Bn,
        float* __restrict__ sim, float* __restrict__ colsum,
        float* __restrict__ acc) {
    __shared__ float cs[512];
    __shared__ float sred[8];
    const int t    = threadIdx.x;
    const int lane = t & 63;
    const int w    = t >> 6;
    const int s    = blockIdx.x & 127;              // this block's residue
    const int kb   = (blockIdx.x >> 7) * 32 + w * 8; // row-multiplier base

    cs[t] = 0.f; cs[t + 256] = 0.f;

    float cacc[8];
#pragma unroll
    for (int k = 0; k < 8; ++k) cacc[k] = 0.f;
    float accLog = 0.f, accSim = 0.f;

#pragma unroll
    for (int batch = 0; batch < 2; ++batch) {
        // ---- 4 rows per batch, all loads issued up front ----
        int rows[4];
        float4 a0[4], a1[4], b0[4], b1[4];
#pragma unroll
        for (int q = 0; q < 4; ++q) {
            rows[q] = s + 128 * (kb + batch * 4 + q);
            const float* a = A  + (size_t)rows[q] * N_COLS;
            const float* b = Bn + (size_t)rows[q] * N_COLS;
            a0[q] = *(const float4*)(a + lane * 4);
            a1[q] = *(const float4*)(a + 256 + lane * 4);
            b0[q] = *(const float4*)(b + lane * 4);
            b1[q] = *(const float4*)(b + 256 + lane * 4);
        }
        // ---- exp + per-lane partials (inputs ~N(0,1): no overflow) ----
        float ea[4][8], sa[4], sb[4], dp[4];
#pragma unroll
        for (int q = 0; q < 4; ++q) {
            float av[8] = {a0[q].x, a0[q].y, a0[q].z, a0[q].w,
                           a1[q].x, a1[q].y, a1[q].z, a1[q].w};
            float bv[8] = {b0[q].x, b0[q].y, b0[q].z, b0[q].w,
                           b1[q].x, b1[q].y, b1[q].z, b1[q].w};
            float sA = 0.f, sB = 0.f, d = 0.f;
#pragma unroll
            for (int k = 0; k < 8; ++k) {
                float e = __expf(av[k]);
                float f = __expf(bv[k]);
                ea[q][k] = e;
                sA += e; sB += f; d += e * f;
            }
            sa[q] = sA; sb[q] = sB; dp[q] = d;
        }
        // ---- 12 independent shuffle chains, pipelined ----
#pragma unroll
        for (int m = 32; m >= 1; m >>= 1) {
#pragma unroll
            for (int q = 0; q < 4; ++q) {
                sa[q] += __shfl_xor(sa[q], m, 64);
                sb[q] += __shfl_xor(sb[q], m, 64);
                dp[q] += __shfl_xor(dp[q], m, 64);
            }
        }
        // ---- emit ----
#pragma unroll
        for (int q = 0; q < 4; ++q) {
            float inv_sa = 1.f / sa[q];
#pragma unroll
            for (int k = 0; k < 8; ++k) cacc[k] += ea[q][k] * inv_sa;
            if (lane == 0) {
                float sv = dp[q] * inv_sa * (1.f / sb[q]);
                sim[rows[q]] = sv;
                float lg = __logf(sv);
                accLog += fmaxf(lg, -100.f);
                accSim += fmaxf(sv, EPS);
            }
        }
    }

    // ---- epilogue: block reduce (all 4 waves share residue s) ----
    if (lane == 0) { sred[w] = accLog; sred[4 + w] = accSim; }
    __syncthreads();
#pragma unroll
    for (int k = 0; k < 4; ++k) atomicAdd(&cs[lane * 4 + k], cacc[k]);
#pragma unroll
    for (int k = 0; k < 4; ++k) atomicAdd(&cs[256 + lane * 4 + k], cacc[4 + k]);
    __syncthreads();

    float* cdst = colsum + (size_t)s * 512;
    atomicAdd(&cdst[t], cs[t]);
    atomicAdd(&cdst[t + 256], cs[t + 256]);
    if (t == 0) atomicAdd(&acc[0], sred[0] + sred[1] + sred[2] + sred[3]);
    if (t == 1) atomicAdd(&acc[1], sred[4] + sred[5] + sred[6] + sred[7]);
}

__global__ __launch_bounds__(512) void k_final(
        const float* __restrict__ colsum, const float* __restrict__ sim,
        const float* __restrict__ acc, float* __restrict__ out) {
    __shared__ float red[16];
    const int t    = threadIdx.x;   // column j = t (0..511)
    const int lane = t & 63;
    const int w    = t >> 6;

    float tot = 0.f, toe = 0.f;
#pragma unroll 4
    for (int s = 0; s < 128; ++s) {
        float c = colsum[s * 512 + t];
        tot += c;
        toe += c * sim[s * 512 + t];
    }
    float p   = fmaxf(tot * (1.f / B_ROWS), EPS);
    float ent = -p * __logf(p);

#pragma unroll
    for (int m = 32; m >= 1; m >>= 1) {
        ent += __shfl_xor(ent, m, 64);
        toe += __shfl_xor(toe, m, 64);
    }
    if (lane == 0) { red[w] = ent; red[8 + w] = toe; }
    __syncthreads();
    if (t == 0) {
        float entropy = 0.f, toeT = 0.f;
#pragma unroll
        for (int i = 0; i < 8; ++i) { entropy += red[i]; toeT += red[8 + i]; }
        float consistency = -acc[0] * (1.f / B_ROWS);
        float second      = acc[1] * EPS;            // sum(max(sim,e)) * 1e-8
        float third       = toeT * EPS * (1.f / N_COLS);
        float third_weight = 0.5f / sqrtf((float)N_COLS);
        float diff_weight  = 0.25f / (float)N_COLS;
        float total = consistency - 2.0f * entropy + diff_weight * second
                      - third_weight * third;
        out[0] = total;
        out[1] = consistency;
        out[2] = entropy;
        out[3] = second;
        out[4] = third;
    }
}

extern "C" void kernel_launch(void* const* d_in, const int* in_sizes, int n_in,
                              void* d_out, int out_size, void* d_ws, size_t ws_size,
                              hipStream_t stream) {
    const float* anchors   = (const float*)d_in[0];
    const float* neighbors = (const float*)d_in[1];
    float* out = (float*)d_out;

    float* sim    = (float*)d_ws;            // 65536 f32
    float* colsum = sim + B_ROWS;            // 128*512 f32 (256 KB)
    float* acc    = colsum + 128 * 512;      // 16 f32

    // zero colsum + acc (sim is fully overwritten by k_main)
    hipMemsetAsync(colsum, 0, (128 * 512 + 16) * sizeof(float), stream);

    k_main<<<dim3(GRID1), dim3(256), 0, stream>>>(
        anchors, neighbors, sim, colsum, acc);
    k_final<<<dim3(1), dim3(512), 0, stream>>>(colsum, sim, acc, out);
}